// Round 8
// baseline (477.844 us; speedup 1.0000x reference)
//
#include <hip/hip_runtime.h>
#include <hip/hip_bf16.h>
#include <cstddef>

// Problem constants (fixed-shape problem)
constexpr int N_NODES = 50000;
constexpr int N_EDGES = 800000;
constexpr int IN_DIM  = 128;
constexpr int HID     = 64;
constexpr int HEADS   = 4;
constexpr int F1      = HEADS * HID;  // 256
constexpr int EMB     = 128;
constexpr int N_GRAPHS = 64;

constexpr int DEG_BLOCKS   = (N_EDGES + 255) / 256;  // 3125
constexpr int SCAN_BLOCKS  = (N_NODES + 255) / 256;  // 196
// per-head W1 fragment size (NT=4, KK=4): 4*4*64*8 bf16 elements
constexpr int W1_FRAG = 4 * 4 * 64 * 8;              // 8192

typedef __bf16 bf16x8 __attribute__((ext_vector_type(8)));
typedef float  f32x4  __attribute__((ext_vector_type(4)));

__device__ __forceinline__ float lrelu(float x) { return x > 0.f ? x : 0.2f * x; }
__device__ __forceinline__ float eluf(float x)  { return x > 0.f ? x : expm1f(x); }

// ---------------------------------------------------------------------------
// Pack a [K x 16*NT] submatrix of B (leading dim ld, origin col0) into
// per-lane MFMA B-fragments, split hi/lo bf16.
// ---------------------------------------------------------------------------
__device__ __forceinline__ void pack_frag(const float* __restrict__ B,
                                          __bf16* __restrict__ hi,
                                          __bf16* __restrict__ lo,
                                          int pblk, int NT, int KK, int ld, int col0) {
    const int gid = pblk * 256 + threadIdx.x;
    if (gid >= NT * KK * 64) return;
    const int lane = gid & 63;
    const int rem  = gid >> 6;
    const int kk   = rem % KK;
    const int t    = rem / KK;
    const int n    = col0 + t * 16 + (lane & 15);
    const int k0   = kk * 32 + (lane >> 4) * 8;
#pragma unroll
    for (int j = 0; j < 8; j++) {
        const float v = B[(size_t)(k0 + j) * ld + n];
        const __bf16 h = (__bf16)v;
        hi[(size_t)gid * 8 + j] = h;
        lo[(size_t)gid * 8 + j] = (__bf16)(v - (float)h);
    }
}

// ---------------------------------------------------------------------------
// prep: [deg histogram | pack W1 per-head | pack W2] by block range.
// ---------------------------------------------------------------------------
__global__ __launch_bounds__(256) void prep_kernel(const int* __restrict__ ei,
                                                   int* __restrict__ deg,
                                                   const float* __restrict__ W1,
                                                   __bf16* __restrict__ B1h,
                                                   __bf16* __restrict__ B1l,
                                                   const float* __restrict__ W2,
                                                   __bf16* __restrict__ B2h,
                                                   __bf16* __restrict__ B2l) {
    const int b = blockIdx.x;
    if (b < DEG_BLOCKS) {
        const int e = b * 256 + threadIdx.x;
        if (e < N_EDGES) atomicAdd(&deg[ei[N_EDGES + e]], 1);
        return;
    }
    const int pb = b - DEG_BLOCKS;
    if (pb < 16) {
        const int head = pb >> 2;
        pack_frag(W1, B1h + head * W1_FRAG, B1l + head * W1_FRAG,
                  pb & 3, 4, 4, F1, head * HID);
    } else {
        pack_frag(W2, B2h, B2l, pb - 16, 8, 8, EMB, 0);
    }
}

// ---------------------------------------------------------------------------
// 3-phase parallel scan (deg -> off); phase C also zeroes cur.
// ---------------------------------------------------------------------------
__global__ __launch_bounds__(256) void scanA_kernel(const int* __restrict__ deg,
                                                    int* __restrict__ off,
                                                    int* __restrict__ partial, int N) {
    __shared__ int sm[256];
    const int t = threadIdx.x;
    const int i = blockIdx.x * 256 + t;
    const int v = (i < N) ? deg[i] : 0;
    sm[t] = v;
    __syncthreads();
    int val = v;
#pragma unroll
    for (int o = 1; o < 256; o <<= 1) {
        const int add = (t >= o) ? sm[t - o] : 0;
        __syncthreads();
        val += add;
        sm[t] = val;
        __syncthreads();
    }
    if (i < N) off[i] = val - v;
    if (t == 255) partial[blockIdx.x] = val;
}

__global__ __launch_bounds__(256) void scanB_kernel(int* __restrict__ partial,
                                                    int* __restrict__ off_last) {
    __shared__ int sm[256];
    const int t = threadIdx.x;
    const int v = (t < SCAN_BLOCKS) ? partial[t] : 0;
    sm[t] = v;
    __syncthreads();
    int val = v;
#pragma unroll
    for (int o = 1; o < 256; o <<= 1) {
        const int add = (t >= o) ? sm[t - o] : 0;
        __syncthreads();
        val += add;
        sm[t] = val;
        __syncthreads();
    }
    if (t < SCAN_BLOCKS) partial[t] = val - v;
    if (t == SCAN_BLOCKS - 1) *off_last = val;
}

__global__ __launch_bounds__(256) void scanC_kernel(int* __restrict__ off,
                                                    const int* __restrict__ partial,
                                                    int* __restrict__ cur, int N) {
    const int i = blockIdx.x * 256 + threadIdx.x;
    if (i < N) {
        off[i] += partial[blockIdx.x];
        cur[i] = 0;
    }
}

// ---------------------------------------------------------------------------
// Split-bf16 MFMA GEMM (+ optional C store) + fused attention logits.
// ---------------------------------------------------------------------------
template <int NT, int KK, int NH, bool ELU_A, bool STORE_C>
__device__ __forceinline__ void gemm_alpha_body(int blk,
                                                const float* __restrict__ A,
                                                const __bf16* __restrict__ Bh,
                                                const __bf16* __restrict__ Bl,
                                                const float* __restrict__ bias,
                                                const float* __restrict__ avs,
                                                const float* __restrict__ avd,
                                                float* __restrict__ C,
                                                float* __restrict__ as_out,
                                                float* __restrict__ ad_out, int M) {
    constexpr int Ncols = NT * 16;
    constexpr int K = KK * 32;
    const int tid  = threadIdx.x;
    const int wave = tid >> 6, lane = tid & 63;
    const int quad = lane >> 4, l16 = lane & 15;
    const int rowA = min(blk * 64 + wave * 16 + l16, M - 1);

    f32x4 acc[NT];
#pragma unroll
    for (int t = 0; t < NT; t++) acc[t] = (f32x4){0.f, 0.f, 0.f, 0.f};

    for (int kk = 0; kk < KK; kk++) {
        const int k0 = kk * 32 + quad * 8;
        float a8[8];
        *(float4*)&a8[0] = *(const float4*)&A[(size_t)rowA * K + k0];
        *(float4*)&a8[4] = *(const float4*)&A[(size_t)rowA * K + k0 + 4];
        if (ELU_A) {
#pragma unroll
            for (int j = 0; j < 8; j++) a8[j] = eluf(a8[j] + bias[k0 + j]);
        }
        bf16x8 ah, al;
#pragma unroll
        for (int j = 0; j < 8; j++) {
            const __bf16 h = (__bf16)a8[j];
            ah[j] = h;
            al[j] = (__bf16)(a8[j] - (float)h);
        }
#pragma unroll
        for (int t = 0; t < NT; t++) {
            const size_t bi = ((size_t)(t * KK + kk) * 64 + lane) * 8;
            bf16x8 bhv = *(const bf16x8*)&Bh[bi];
            bf16x8 blv = *(const bf16x8*)&Bl[bi];
            acc[t] = __builtin_amdgcn_mfma_f32_16x16x32_bf16(ah, bhv, acc[t], 0, 0, 0);
            acc[t] = __builtin_amdgcn_mfma_f32_16x16x32_bf16(al, bhv, acc[t], 0, 0, 0);
            acc[t] = __builtin_amdgcn_mfma_f32_16x16x32_bf16(ah, blv, acc[t], 0, 0, 0);
        }
    }

    const int rowS = blk * 64 + wave * 16 + quad * 4;
    if (STORE_C) {
#pragma unroll
        for (int t = 0; t < NT; t++) {
#pragma unroll
            for (int r = 0; r < 4; r++) {
                const int rr = rowS + r;
                if (rr < M) C[(size_t)rr * Ncols + t * 16 + l16] = acc[t][r];
            }
        }
    }

#pragma unroll
    for (int r = 0; r < 4; r++) {
        float ps[NH], pd[NH];
#pragma unroll
        for (int h = 0; h < NH; h++) { ps[h] = 0.f; pd[h] = 0.f; }
#pragma unroll
        for (int t = 0; t < NT; t++) {
            const int h = (t * 16) / (Ncols / NH);
            const int col = t * 16 + l16;
            ps[h] += acc[t][r] * avs[col];
            pd[h] += acc[t][r] * avd[col];
        }
#pragma unroll
        for (int o = 1; o < 16; o <<= 1) {
#pragma unroll
            for (int h = 0; h < NH; h++) {
                ps[h] += __shfl_xor(ps[h], o);
                pd[h] += __shfl_xor(pd[h], o);
            }
        }
        const int rr = rowS + r;
        if (l16 == 0 && rr < M) {
#pragma unroll
            for (int h = 0; h < NH; h++) {
                as_out[rr * NH + h] = ps[h];
                ad_out[rr * NH + h] = pd[h];
            }
        }
    }
}

// gemm1: x -> as1/ad1 only (no C store).
__global__ __launch_bounds__(256) void gemm1_kernel(
        const float* __restrict__ A, const __bf16* __restrict__ Bh,
        const __bf16* __restrict__ Bl, const float* __restrict__ avs,
        const float* __restrict__ avd, float* __restrict__ as_out,
        float* __restrict__ ad_out, int M) {
    gemm_alpha_body<F1 / 16, IN_DIM / 32, HEADS, false, false>(
        blockIdx.x, A, Bh, Bl, nullptr, avs, avd, nullptr, as_out, ad_out, M);
}

// CSR scatter fused with layer-1 edge-weight computation (as1/ad1 ready).
__global__ __launch_bounds__(256) void scatter_w1_kernel(
        const int* __restrict__ ei, const int* __restrict__ off,
        int* __restrict__ cur, int* __restrict__ col, int* __restrict__ row,
        const float* __restrict__ as1, const float* __restrict__ ad1,
        float4* __restrict__ w4, int E) {
    const int e = blockIdx.x * 256 + threadIdx.x;
    if (e >= E) return;
    const int s = ei[e], d = ei[E + e];
    const int pos = atomicAdd(&cur[d], 1);
    const int slot = off[d] + pos;
    col[slot] = s;
    row[slot] = d;
    const float4 a = *(const float4*)&as1[s * HEADS];
    const float4 b = *(const float4*)&ad1[d * HEADS];
    float4 o;
    o.x = expf(lrelu(a.x + b.x));
    o.y = expf(lrelu(a.y + b.y));
    o.z = expf(lrelu(a.z + b.z));
    o.w = expf(lrelu(a.w + b.w));
    w4[slot] = o;
}

__global__ __launch_bounds__(256) void gemm2_kernel(
        const float* __restrict__ A, const __bf16* __restrict__ Bh,
        const __bf16* __restrict__ Bl, const float* __restrict__ bias,
        const float* __restrict__ avs, const float* __restrict__ avd,
        float* __restrict__ C, float* __restrict__ as_out,
        float* __restrict__ ad_out, int M) {
    gemm_alpha_body<EMB / 16, F1 / 32, 1, true, true>(
        blockIdx.x, A, Bh, Bl, bias, avs, avd, C, as_out, ad_out, M);
}

// Layer-2 edge weights (one exp per edge instead of 64).
__global__ __launch_bounds__(256) void w2_kernel(const int* __restrict__ col,
                                                 const int* __restrict__ row,
                                                 const float* __restrict__ as2,
                                                 const float* __restrict__ ad2,
                                                 float* __restrict__ w2, int E) {
    const int i = blockIdx.x * 256 + threadIdx.x;
    if (i >= E) return;
    w2[i] = expf(lrelu(as2[col[i]] + ad2[row[i]]));
}

// ---------------------------------------------------------------------------
// Layer-1 x-aggregation: one wave per dst node. w forced into an SGPR so
// off/as1/ad1/col/w4 accesses compile to scalar loads (s_load) — the 64-lane
// redundant vector loads of wave-uniform addresses were ~1/3 of VALUBusy.
// ---------------------------------------------------------------------------
__global__ __launch_bounds__(256) void agg1x_kernel(const int* __restrict__ off,
                                                    const int* __restrict__ col,
                                                    const float4* __restrict__ w4,
                                                    const float* __restrict__ x,
                                                    const float* __restrict__ as1,
                                                    const float* __restrict__ ad1,
                                                    float* __restrict__ aggx, int N) {
    const int w = __builtin_amdgcn_readfirstlane((blockIdx.x * 256 + threadIdx.x) >> 6);
    const int lane = threadIdx.x & 63;
    if (w >= N) return;

    float2 acc[HEADS];
    float z[HEADS];
#pragma unroll
    for (int h = 0; h < HEADS; h++) { acc[h] = make_float2(0.f, 0.f); z[h] = 0.f; }

    {   // self-loop (scalar as1/ad1 loads)
        const float4 asv = *(const float4*)&as1[w * HEADS];
        const float4 adv = *(const float4*)&ad1[w * HEADS];
        const float2 xv = *(const float2*)&x[(size_t)w * IN_DIM + lane * 2];
        float ws[HEADS] = {expf(lrelu(asv.x + adv.x)), expf(lrelu(asv.y + adv.y)),
                           expf(lrelu(asv.z + adv.z)), expf(lrelu(asv.w + adv.w))};
#pragma unroll
        for (int h = 0; h < HEADS; h++) {
            acc[h].x += ws[h] * xv.x; acc[h].y += ws[h] * xv.y; z[h] += ws[h];
        }
    }
    const int jb = off[w], je = off[w + 1];
    int j = jb;
    for (; j + 3 < je; j += 4) {
        const int s0 = col[j], s1 = col[j + 1], s2 = col[j + 2], s3 = col[j + 3];
        const float4 w0 = w4[j], w1 = w4[j + 1], w2 = w4[j + 2], w3 = w4[j + 3];
        const float2 v0 = *(const float2*)&x[(size_t)s0 * IN_DIM + lane * 2];
        const float2 v1 = *(const float2*)&x[(size_t)s1 * IN_DIM + lane * 2];
        const float2 v2 = *(const float2*)&x[(size_t)s2 * IN_DIM + lane * 2];
        const float2 v3 = *(const float2*)&x[(size_t)s3 * IN_DIM + lane * 2];
        acc[0].x += w0.x * v0.x + w1.x * v1.x + w2.x * v2.x + w3.x * v3.x;
        acc[0].y += w0.x * v0.y + w1.x * v1.y + w2.x * v2.y + w3.x * v3.y;
        acc[1].x += w0.y * v0.x + w1.y * v1.x + w2.y * v2.x + w3.y * v3.x;
        acc[1].y += w0.y * v0.y + w1.y * v1.y + w2.y * v2.y + w3.y * v3.y;
        acc[2].x += w0.z * v0.x + w1.z * v1.x + w2.z * v2.x + w3.z * v3.x;
        acc[2].y += w0.z * v0.y + w1.z * v1.y + w2.z * v2.y + w3.z * v3.y;
        acc[3].x += w0.w * v0.x + w1.w * v1.x + w2.w * v2.x + w3.w * v3.x;
        acc[3].y += w0.w * v0.y + w1.w * v1.y + w2.w * v2.y + w3.w * v3.y;
        z[0] += (w0.x + w1.x) + (w2.x + w3.x);
        z[1] += (w0.y + w1.y) + (w2.y + w3.y);
        z[2] += (w0.z + w1.z) + (w2.z + w3.z);
        z[3] += (w0.w + w1.w) + (w2.w + w3.w);
    }
    for (; j < je; j++) {
        const int s0 = col[j];
        const float4 w0 = w4[j];
        const float2 v0 = *(const float2*)&x[(size_t)s0 * IN_DIM + lane * 2];
        acc[0].x += w0.x * v0.x; acc[0].y += w0.x * v0.y; z[0] += w0.x;
        acc[1].x += w0.y * v0.x; acc[1].y += w0.y * v0.y; z[1] += w0.y;
        acc[2].x += w0.z * v0.x; acc[2].y += w0.z * v0.y; z[2] += w0.z;
        acc[3].x += w0.w * v0.x; acc[3].y += w0.w * v0.y; z[3] += w0.w;
    }
#pragma unroll
    for (int h = 0; h < HEADS; h++) {
        const float inv = 1.f / z[h];
        float2 o = make_float2(acc[h].x * inv, acc[h].y * inv);
        *(float2*)&aggx[((size_t)w * HEADS + h) * IN_DIM + lane * 2] = o;
    }
}

// ---------------------------------------------------------------------------
// Head-GEMM: out1[:, h*64:(h+1)*64] = aggx[:, h, :] @ W1[:, h*64:(h+1)*64]
// ---------------------------------------------------------------------------
__global__ __launch_bounds__(256) void gemm_bd_kernel(const float* __restrict__ aggx,
                                                      const __bf16* __restrict__ B1h,
                                                      const __bf16* __restrict__ B1l,
                                                      float* __restrict__ out1, int M) {
    constexpr int NT = 4, KK = 4;
    const int head = blockIdx.y;
    const int blk = blockIdx.x;
    const int tid  = threadIdx.x;
    const int wave = tid >> 6, lane = tid & 63;
    const int quad = lane >> 4, l16 = lane & 15;
    const int rowA = min(blk * 64 + wave * 16 + l16, M - 1);
    const float* Arow = aggx + ((size_t)rowA * HEADS + head) * IN_DIM;
    const __bf16* Bh = B1h + head * W1_FRAG;
    const __bf16* Bl = B1l + head * W1_FRAG;

    f32x4 acc[NT];
#pragma unroll
    for (int t = 0; t < NT; t++) acc[t] = (f32x4){0.f, 0.f, 0.f, 0.f};

    for (int kk = 0; kk < KK; kk++) {
        const int k0 = kk * 32 + quad * 8;
        float a8[8];
        *(float4*)&a8[0] = *(const float4*)&Arow[k0];
        *(float4*)&a8[4] = *(const float4*)&Arow[k0 + 4];
        bf16x8 ah, al;
#pragma unroll
        for (int j = 0; j < 8; j++) {
            const __bf16 h = (__bf16)a8[j];
            ah[j] = h;
            al[j] = (__bf16)(a8[j] - (float)h);
        }
#pragma unroll
        for (int t = 0; t < NT; t++) {
            const size_t bi = ((size_t)(t * KK + kk) * 64 + lane) * 8;
            bf16x8 bhv = *(const bf16x8*)&Bh[bi];
            bf16x8 blv = *(const bf16x8*)&Bl[bi];
            acc[t] = __builtin_amdgcn_mfma_f32_16x16x32_bf16(ah, bhv, acc[t], 0, 0, 0);
            acc[t] = __builtin_amdgcn_mfma_f32_16x16x32_bf16(al, bhv, acc[t], 0, 0, 0);
            acc[t] = __builtin_amdgcn_mfma_f32_16x16x32_bf16(ah, blv, acc[t], 0, 0, 0);
        }
    }

    const int rowS = blk * 64 + wave * 16 + quad * 4;
#pragma unroll
    for (int t = 0; t < NT; t++) {
#pragma unroll
        for (int r = 0; r < 4; r++) {
            const int rr = rowS + r;
            if (rr < M) out1[(size_t)rr * F1 + head * HID + t * 16 + l16] = acc[t][r];
        }
    }
}

// ---------------------------------------------------------------------------
// Layer-2 aggregation: one wave per dst node, precomputed scalar weights.
// ---------------------------------------------------------------------------
__global__ __launch_bounds__(256) void agg2_kernel(const int* __restrict__ off,
                                                   const int* __restrict__ col,
                                                   const float* __restrict__ w2,
                                                   const float* __restrict__ g2,
                                                   const float* __restrict__ as2,
                                                   const float* __restrict__ ad2,
                                                   float* __restrict__ out2, int N) {
    const int w = __builtin_amdgcn_readfirstlane((blockIdx.x * 256 + threadIdx.x) >> 6);
    const int lane = threadIdx.x & 63;
    if (w >= N) return;

    float2 acc = make_float2(0.f, 0.f);
    float z = 0.f;
    {   // self-loop
        const float wt = expf(lrelu(as2[w] + ad2[w]));
        float2 hv = *(const float2*)&g2[(size_t)w * EMB + lane * 2];
        acc.x += wt * hv.x; acc.y += wt * hv.y;
        z += wt;
    }
    const int jb = off[w], je = off[w + 1];
    int j = jb;
    for (; j + 3 < je; j += 4) {
        const int s0 = col[j], s1 = col[j + 1], s2 = col[j + 2], s3 = col[j + 3];
        const float w0 = w2[j], w1 = w2[j + 1], w2v = w2[j + 2], w3 = w2[j + 3];
        const float2 v0 = *(const float2*)&g2[(size_t)s0 * EMB + lane * 2];
        const float2 v1 = *(const float2*)&g2[(size_t)s1 * EMB + lane * 2];
        const float2 v2 = *(const float2*)&g2[(size_t)s2 * EMB + lane * 2];
        const float2 v3 = *(const float2*)&g2[(size_t)s3 * EMB + lane * 2];
        acc.x += w0 * v0.x + w1 * v1.x + w2v * v2.x + w3 * v3.x;
        acc.y += w0 * v0.y + w1 * v1.y + w2v * v2.y + w3 * v3.y;
        z += (w0 + w1) + (w2v + w3);
    }
    for (; j < je; j++) {
        const int s0 = col[j];
        const float w0 = w2[j];
        const float2 v0 = *(const float2*)&g2[(size_t)s0 * EMB + lane * 2];
        acc.x += w0 * v0.x; acc.y += w0 * v0.y;
        z += w0;
    }
    const float inv = 1.f / z;
    float2 o = make_float2(acc.x * inv, acc.y * inv);
    *(float2*)&out2[(size_t)w * EMB + lane * 2] = o;
}

// ---------------------------------------------------------------------------
// Global mean pool (782-block run-length form) + divide.
// ---------------------------------------------------------------------------
__global__ __launch_bounds__(128) void pool_kernel(const float* __restrict__ out2,
                                                   const float* __restrict__ b2,
                                                   const int* __restrict__ batch,
                                                   float* __restrict__ pool,
                                                   float* __restrict__ cnt, int N) {
    const int c = threadIdx.x;
    const int n0 = blockIdx.x * 64;
    const int nend = min(n0 + 64, N);
    const float bias = b2[c];
    float acc = 0.f, cacc = 0.f;
    int curg = batch[n0];
    for (int n = n0; n < nend; n++) {
        const int g = batch[n];
        if (g != curg) {
            atomicAdd(&pool[curg * EMB + c], acc);
            if (c == 0) atomicAdd(&cnt[curg], cacc);
            acc = 0.f; cacc = 0.f; curg = g;
        }
        float v = out2[(size_t)n * EMB + c] + bias;
        v = v > 0.f ? v : expm1f(v);
        acc += v;
        cacc += 1.f;
    }
    atomicAdd(&pool[curg * EMB + c], acc);
    if (c == 0) atomicAdd(&cnt[curg], cacc);
}

__global__ __launch_bounds__(256) void div_kernel(const float* __restrict__ pool,
                                                  const float* __restrict__ cnt,
                                                  float* __restrict__ out) {
    const int i = blockIdx.x * 256 + threadIdx.x;
    out[i] = pool[i] / fmaxf(cnt[i >> 7], 1.f);
}

// ---------------------------------------------------------------------------
extern "C" void kernel_launch(void* const* d_in, const int* in_sizes, int n_in,
                              void* d_out, int out_size, void* d_ws, size_t ws_size,
                              hipStream_t stream) {
    const float* x      = (const float*)d_in[0];
    const int*   ei     = (const int*)d_in[1];
    const int*   batch  = (const int*)d_in[3];
    const float* W1     = (const float*)d_in[4];
    const float* a_src1 = (const float*)d_in[5];
    const float* a_dst1 = (const float*)d_in[6];
    const float* b1     = (const float*)d_in[7];
    const float* W2     = (const float*)d_in[8];
    const float* a_src2 = (const float*)d_in[9];
    const float* a_dst2 = (const float*)d_in[10];
    const float* b2     = (const float*)d_in[11];
    float* out = (float*)d_out;

    const int N = N_NODES, E = N_EDGES;

    size_t cur_off = 0;
    auto carve = [&](size_t bytes) {
        size_t o = cur_off;
        cur_off = (cur_off + bytes + 255) & ~(size_t)255;
        return (char*)d_ws + o;
    };
    // zero-init region: deg + pool + cnt
    int* deg     = (int*)carve((size_t)N * 4);
    float* pool  = (float*)carve((size_t)N_GRAPHS * EMB * 4);
    float* cnt   = (float*)carve((size_t)N_GRAPHS * 4);
    const size_t zero_bytes = cur_off;
    int* curp    = (int*)carve((size_t)N * 4);
    int* partial = (int*)carve((size_t)SCAN_BLOCKS * 4);
    __bf16* B1h  = (__bf16*)carve((size_t)HEADS * W1_FRAG * 2);
    __bf16* B1l  = (__bf16*)carve((size_t)HEADS * W1_FRAG * 2);
    __bf16* B2h  = (__bf16*)carve((size_t)F1 * EMB * 2);
    __bf16* B2l  = (__bf16*)carve((size_t)F1 * EMB * 2);
    int* off     = (int*)carve((size_t)(N + 1) * 4);
    int* col     = (int*)carve((size_t)E * 4);
    int* rowd    = (int*)carve((size_t)E * 4);
    float4* w4   = (float4*)carve((size_t)E * 16);
    float* w2    = (float*)carve((size_t)E * 4);
    float* aggx  = (float*)carve((size_t)N * HEADS * IN_DIM * 4);
    float* out1  = (float*)carve((size_t)N * F1 * 4);
    float* g2    = (float*)carve((size_t)N * EMB * 4);
    float* out2  = (float*)carve((size_t)N * EMB * 4);
    float* as1   = (float*)carve((size_t)N * HEADS * 4);
    float* ad1   = (float*)carve((size_t)N * HEADS * 4);
    float* as2   = (float*)carve((size_t)N * 4);
    float* ad2   = (float*)carve((size_t)N * 4);

    hipMemsetAsync(d_ws, 0, zero_bytes, stream);

    prep_kernel<<<DEG_BLOCKS + 32, 256, 0, stream>>>(ei, deg, W1, B1h, B1l, W2, B2h, B2l);

    scanA_kernel<<<SCAN_BLOCKS, 256, 0, stream>>>(deg, off, partial, N);
    scanB_kernel<<<1, 256, 0, stream>>>(partial, &off[N]);
    scanC_kernel<<<SCAN_BLOCKS, 256, 0, stream>>>(off, partial, curp, N);

    // gemm1 (x -> as1/ad1), then scatter fused with edge-weight computation
    gemm1_kernel<<<(N + 63) / 64, 256, 0, stream>>>(x, B1h, B1l, a_src1, a_dst1,
                                                    as1, ad1, N);
    scatter_w1_kernel<<<DEG_BLOCKS, 256, 0, stream>>>(ei, off, curp, col, rowd,
                                                      as1, ad1, w4, E);

    agg1x_kernel<<<(N + 3) / 4, 256, 0, stream>>>(off, col, w4, x, as1, ad1, aggx, N);

    gemm_bd_kernel<<<dim3((N + 63) / 64, HEADS), 256, 0, stream>>>(aggx, B1h, B1l, out1, N);

    gemm2_kernel<<<(N + 63) / 64, 256, 0, stream>>>(out1, B2h, B2l, b1, a_src2, a_dst2,
                                                    g2, as2, ad2, N);
    w2_kernel<<<DEG_BLOCKS, 256, 0, stream>>>(col, rowd, as2, ad2, w2, E);
    agg2_kernel<<<(N + 3) / 4, 256, 0, stream>>>(off, col, w2, g2, as2, ad2, out2, N);

    pool_kernel<<<(N + 63) / 64, 128, 0, stream>>>(out2, b2, batch, pool, cnt, N);
    div_kernel<<<(N_GRAPHS * EMB) / 256, 256, 0, stream>>>(pool, cnt, out);
}

// Round 9
// 469.381 us; speedup vs baseline: 1.0180x; 1.0180x over previous
//
#include <hip/hip_runtime.h>
#include <hip/hip_bf16.h>
#include <cstddef>

// Problem constants (fixed-shape problem)
constexpr int N_NODES = 50000;
constexpr int N_EDGES = 800000;
constexpr int IN_DIM  = 128;
constexpr int HID     = 64;
constexpr int HEADS   = 4;
constexpr int F1      = HEADS * HID;  // 256
constexpr int EMB     = 128;
constexpr int N_GRAPHS = 64;

constexpr int DEG_BLOCKS   = (N_EDGES + 255) / 256;  // 3125
constexpr int SCAN_BLOCKS  = (N_NODES + 255) / 256;  // 196
// per-head W1 fragment size (NT=4, KK=4): 4*4*64*8 bf16 elements
constexpr int W1_FRAG = 4 * 4 * 64 * 8;              // 8192
// LDS row stride (f32) for the fused kernel: 256 + 12 pad -> phase-2
// ds_read_b128 starts spread over all 32 banks (2-way max, free);
// writes land 2-way as well. 32*268*4 = 34.3 KB (4 blocks/CU).
constexpr int LDP = 268;

typedef __bf16 bf16x8 __attribute__((ext_vector_type(8)));
typedef float  f32x4  __attribute__((ext_vector_type(4)));

__device__ __forceinline__ float lrelu(float x) { return x > 0.f ? x : 0.2f * x; }
__device__ __forceinline__ float eluf(float x)  { return x > 0.f ? x : expm1f(x); }

// ---------------------------------------------------------------------------
// Pack a [K x 16*NT] submatrix of B (leading dim ld, origin col0) into
// per-lane MFMA B-fragments, split hi/lo bf16.
// ---------------------------------------------------------------------------
__device__ __forceinline__ void pack_frag(const float* __restrict__ B,
                                          __bf16* __restrict__ hi,
                                          __bf16* __restrict__ lo,
                                          int pblk, int NT, int KK, int ld, int col0) {
    const int gid = pblk * 256 + threadIdx.x;
    if (gid >= NT * KK * 64) return;
    const int lane = gid & 63;
    const int rem  = gid >> 6;
    const int kk   = rem % KK;
    const int t    = rem / KK;
    const int n    = col0 + t * 16 + (lane & 15);
    const int k0   = kk * 32 + (lane >> 4) * 8;
#pragma unroll
    for (int j = 0; j < 8; j++) {
        const float v = B[(size_t)(k0 + j) * ld + n];
        const __bf16 h = (__bf16)v;
        hi[(size_t)gid * 8 + j] = h;
        lo[(size_t)gid * 8 + j] = (__bf16)(v - (float)h);
    }
}

// ---------------------------------------------------------------------------
// prep: [deg histogram | pack W1 per-head | pack W2] by block range.
// ---------------------------------------------------------------------------
__global__ __launch_bounds__(256) void prep_kernel(const int* __restrict__ ei,
                                                   int* __restrict__ deg,
                                                   const float* __restrict__ W1,
                                                   __bf16* __restrict__ B1h,
                                                   __bf16* __restrict__ B1l,
                                                   const float* __restrict__ W2,
                                                   __bf16* __restrict__ B2h,
                                                   __bf16* __restrict__ B2l) {
    const int b = blockIdx.x;
    if (b < DEG_BLOCKS) {
        const int e = b * 256 + threadIdx.x;
        if (e < N_EDGES) atomicAdd(&deg[ei[N_EDGES + e]], 1);
        return;
    }
    const int pb = b - DEG_BLOCKS;
    if (pb < 16) {
        const int head = pb >> 2;
        pack_frag(W1, B1h + head * W1_FRAG, B1l + head * W1_FRAG,
                  pb & 3, 4, 4, F1, head * HID);
    } else {
        pack_frag(W2, B2h, B2l, pb - 16, 8, 8, EMB, 0);
    }
}

// ---------------------------------------------------------------------------
// 3-phase parallel scan (deg -> off); phase C also zeroes cur.
// ---------------------------------------------------------------------------
__global__ __launch_bounds__(256) void scanA_kernel(const int* __restrict__ deg,
                                                    int* __restrict__ off,
                                                    int* __restrict__ partial, int N) {
    __shared__ int sm[256];
    const int t = threadIdx.x;
    const int i = blockIdx.x * 256 + t;
    const int v = (i < N) ? deg[i] : 0;
    sm[t] = v;
    __syncthreads();
    int val = v;
#pragma unroll
    for (int o = 1; o < 256; o <<= 1) {
        const int add = (t >= o) ? sm[t - o] : 0;
        __syncthreads();
        val += add;
        sm[t] = val;
        __syncthreads();
    }
    if (i < N) off[i] = val - v;
    if (t == 255) partial[blockIdx.x] = val;
}

__global__ __launch_bounds__(256) void scanB_kernel(int* __restrict__ partial,
                                                    int* __restrict__ off_last) {
    __shared__ int sm[256];
    const int t = threadIdx.x;
    const int v = (t < SCAN_BLOCKS) ? partial[t] : 0;
    sm[t] = v;
    __syncthreads();
    int val = v;
#pragma unroll
    for (int o = 1; o < 256; o <<= 1) {
        const int add = (t >= o) ? sm[t - o] : 0;
        __syncthreads();
        val += add;
        sm[t] = val;
        __syncthreads();
    }
    if (t < SCAN_BLOCKS) partial[t] = val - v;
    if (t == SCAN_BLOCKS - 1) *off_last = val;
}

__global__ __launch_bounds__(256) void scanC_kernel(int* __restrict__ off,
                                                    const int* __restrict__ partial,
                                                    int* __restrict__ cur, int N) {
    const int i = blockIdx.x * 256 + threadIdx.x;
    if (i < N) {
        off[i] += partial[blockIdx.x];
        cur[i] = 0;
    }
}

// ---------------------------------------------------------------------------
// gemm1: as1/ad1 = alpha-logits of (x @ W1). No C store.
// ---------------------------------------------------------------------------
__global__ __launch_bounds__(256) void gemm1_kernel(
        const float* __restrict__ A, const __bf16* __restrict__ Bh,
        const __bf16* __restrict__ Bl, const float* __restrict__ avs,
        const float* __restrict__ avd, float* __restrict__ as_out,
        float* __restrict__ ad_out, int M) {
    constexpr int NT = F1 / 16, KK = IN_DIM / 32, NH = HEADS;
    constexpr int Ncols = NT * 16;
    constexpr int K = KK * 32;
    const int tid  = threadIdx.x;
    const int wave = tid >> 6, lane = tid & 63;
    const int quad = lane >> 4, l16 = lane & 15;
    const int rowA = min((int)blockIdx.x * 64 + wave * 16 + l16, M - 1);

    f32x4 acc[NT];
#pragma unroll
    for (int t = 0; t < NT; t++) acc[t] = (f32x4){0.f, 0.f, 0.f, 0.f};

    for (int kk = 0; kk < KK; kk++) {
        const int k0 = kk * 32 + quad * 8;
        float a8[8];
        *(float4*)&a8[0] = *(const float4*)&A[(size_t)rowA * K + k0];
        *(float4*)&a8[4] = *(const float4*)&A[(size_t)rowA * K + k0 + 4];
        bf16x8 ah, al;
#pragma unroll
        for (int j = 0; j < 8; j++) {
            const __bf16 h = (__bf16)a8[j];
            ah[j] = h;
            al[j] = (__bf16)(a8[j] - (float)h);
        }
#pragma unroll
        for (int t = 0; t < NT; t++) {
            const size_t bi = ((size_t)(t * KK + kk) * 64 + lane) * 8;
            bf16x8 bhv = *(const bf16x8*)&Bh[bi];
            bf16x8 blv = *(const bf16x8*)&Bl[bi];
            acc[t] = __builtin_amdgcn_mfma_f32_16x16x32_bf16(ah, bhv, acc[t], 0, 0, 0);
            acc[t] = __builtin_amdgcn_mfma_f32_16x16x32_bf16(al, bhv, acc[t], 0, 0, 0);
            acc[t] = __builtin_amdgcn_mfma_f32_16x16x32_bf16(ah, blv, acc[t], 0, 0, 0);
        }
    }

    const int rowS = blockIdx.x * 64 + wave * 16 + quad * 4;
#pragma unroll
    for (int r = 0; r < 4; r++) {
        float ps[NH], pd[NH];
#pragma unroll
        for (int h = 0; h < NH; h++) { ps[h] = 0.f; pd[h] = 0.f; }
#pragma unroll
        for (int t = 0; t < NT; t++) {
            const int h = (t * 16) / (Ncols / NH);
            const int col = t * 16 + l16;
            ps[h] += acc[t][r] * avs[col];
            pd[h] += acc[t][r] * avd[col];
        }
#pragma unroll
        for (int o = 1; o < 16; o <<= 1) {
#pragma unroll
            for (int h = 0; h < NH; h++) {
                ps[h] += __shfl_xor(ps[h], o);
                pd[h] += __shfl_xor(pd[h], o);
            }
        }
        const int rr = rowS + r;
        if (l16 == 0 && rr < M) {
#pragma unroll
            for (int h = 0; h < NH; h++) {
                as_out[rr * NH + h] = ps[h];
                ad_out[rr * NH + h] = pd[h];
            }
        }
    }
}

// CSR scatter fused with layer-1 edge-weight computation (as1/ad1 ready).
__global__ __launch_bounds__(256) void scatter_w1_kernel(
        const int* __restrict__ ei, const int* __restrict__ off,
        int* __restrict__ cur, int* __restrict__ col, int* __restrict__ row,
        const float* __restrict__ as1, const float* __restrict__ ad1,
        float4* __restrict__ w4, int E) {
    const int e = blockIdx.x * 256 + threadIdx.x;
    if (e >= E) return;
    const int s = ei[e], d = ei[E + e];
    const int pos = atomicAdd(&cur[d], 1);
    const int slot = off[d] + pos;
    col[slot] = s;
    row[slot] = d;
    const float4 a = *(const float4*)&as1[s * HEADS];
    const float4 b = *(const float4*)&ad1[d * HEADS];
    float4 o;
    o.x = expf(lrelu(a.x + b.x));
    o.y = expf(lrelu(a.y + b.y));
    o.z = expf(lrelu(a.z + b.z));
    o.w = expf(lrelu(a.w + b.w));
    w4[slot] = o;
}

// Layer-2 edge weights (one exp per edge instead of 64).
__global__ __launch_bounds__(256) void w2_kernel(const int* __restrict__ col,
                                                 const int* __restrict__ row,
                                                 const float* __restrict__ as2,
                                                 const float* __restrict__ ad2,
                                                 float* __restrict__ w2, int E) {
    const int i = blockIdx.x * 256 + threadIdx.x;
    if (i >= E) return;
    w2[i] = expf(lrelu(as2[col[i]] + ad2[row[i]]));
}

// ---------------------------------------------------------------------------
// Layer-1 x-aggregation: one wave per dst node, scalarized uniform accesses,
// 4-edge unroll. aggx[node][head][:] = (sum_e w_e x[src_e]) / z_h.
// ---------------------------------------------------------------------------
__global__ __launch_bounds__(256) void agg1x_kernel(const int* __restrict__ off,
                                                    const int* __restrict__ col,
                                                    const float4* __restrict__ w4,
                                                    const float* __restrict__ x,
                                                    const float* __restrict__ as1,
                                                    const float* __restrict__ ad1,
                                                    float* __restrict__ aggx, int N) {
    const int w = __builtin_amdgcn_readfirstlane((blockIdx.x * 256 + threadIdx.x) >> 6);
    const int lane = threadIdx.x & 63;
    if (w >= N) return;

    float2 acc[HEADS];
    float z[HEADS];
#pragma unroll
    for (int h = 0; h < HEADS; h++) { acc[h] = make_float2(0.f, 0.f); z[h] = 0.f; }

    {   // self-loop
        const float4 asv = *(const float4*)&as1[w * HEADS];
        const float4 adv = *(const float4*)&ad1[w * HEADS];
        const float2 xv = *(const float2*)&x[(size_t)w * IN_DIM + lane * 2];
        float ws[HEADS] = {expf(lrelu(asv.x + adv.x)), expf(lrelu(asv.y + adv.y)),
                           expf(lrelu(asv.z + adv.z)), expf(lrelu(asv.w + adv.w))};
#pragma unroll
        for (int h = 0; h < HEADS; h++) {
            acc[h].x += ws[h] * xv.x; acc[h].y += ws[h] * xv.y; z[h] += ws[h];
        }
    }
    const int jb = off[w], je = off[w + 1];
    int j = jb;
    for (; j + 3 < je; j += 4) {
        const int s0 = col[j], s1 = col[j + 1], s2 = col[j + 2], s3 = col[j + 3];
        const float4 w0 = w4[j], w1 = w4[j + 1], w2 = w4[j + 2], w3 = w4[j + 3];
        const float2 v0 = *(const float2*)&x[(size_t)s0 * IN_DIM + lane * 2];
        const float2 v1 = *(const float2*)&x[(size_t)s1 * IN_DIM + lane * 2];
        const float2 v2 = *(const float2*)&x[(size_t)s2 * IN_DIM + lane * 2];
        const float2 v3 = *(const float2*)&x[(size_t)s3 * IN_DIM + lane * 2];
        acc[0].x += w0.x * v0.x + w1.x * v1.x + w2.x * v2.x + w3.x * v3.x;
        acc[0].y += w0.x * v0.y + w1.x * v1.y + w2.x * v2.y + w3.x * v3.y;
        acc[1].x += w0.y * v0.x + w1.y * v1.x + w2.y * v2.x + w3.y * v3.x;
        acc[1].y += w0.y * v0.y + w1.y * v1.y + w2.y * v2.y + w3.y * v3.y;
        acc[2].x += w0.z * v0.x + w1.z * v1.x + w2.z * v2.x + w3.z * v3.x;
        acc[2].y += w0.z * v0.y + w1.z * v1.y + w2.z * v2.y + w3.z * v3.y;
        acc[3].x += w0.w * v0.x + w1.w * v1.x + w2.w * v2.x + w3.w * v3.x;
        acc[3].y += w0.w * v0.y + w1.w * v1.y + w2.w * v2.y + w3.w * v3.y;
        z[0] += (w0.x + w1.x) + (w2.x + w3.x);
        z[1] += (w0.y + w1.y) + (w2.y + w3.y);
        z[2] += (w0.z + w1.z) + (w2.z + w3.z);
        z[3] += (w0.w + w1.w) + (w2.w + w3.w);
    }
    for (; j < je; j++) {
        const int s0 = col[j];
        const float4 w0 = w4[j];
        const float2 v0 = *(const float2*)&x[(size_t)s0 * IN_DIM + lane * 2];
        acc[0].x += w0.x * v0.x; acc[0].y += w0.x * v0.y; z[0] += w0.x;
        acc[1].x += w0.y * v0.x; acc[1].y += w0.y * v0.y; z[1] += w0.y;
        acc[2].x += w0.z * v0.x; acc[2].y += w0.z * v0.y; z[2] += w0.z;
        acc[3].x += w0.w * v0.x; acc[3].y += w0.w * v0.y; z[3] += w0.w;
    }
#pragma unroll
    for (int h = 0; h < HEADS; h++) {
        const float inv = 1.f / z[h];
        float2 o = make_float2(acc[h].x * inv, acc[h].y * inv);
        *(float2*)&aggx[((size_t)w * HEADS + h) * IN_DIM + lane * 2] = o;
    }
}

// ---------------------------------------------------------------------------
// FUSED layer-1-reconstruct + layer-2 GEMM (replaces gemm_bd + gemm2):
//   phase 1: h-tile = aggx @ W1 (per head), ELU(+b1) -> LDS (wave-private rows)
//   phase 2: g2 = h-tile @ W2 from LDS, + alpha2 logits
// Deletes the out1 buffer (51 MB write + 51 MB read) and one dispatch.
// 32 rows/block, 2 waves (128 thr). LDS 32*268*4 = 34.3 KB -> 4 blocks/CU.
// ---------------------------------------------------------------------------
__global__ __launch_bounds__(128) void gemm12_kernel(
        const float* __restrict__ aggx,
        const __bf16* __restrict__ B1h, const __bf16* __restrict__ B1l,
        const float* __restrict__ b1,
        const __bf16* __restrict__ B2h, const __bf16* __restrict__ B2l,
        const float* __restrict__ avs, const float* __restrict__ avd,
        float* __restrict__ g2, float* __restrict__ as_out,
        float* __restrict__ ad_out, int M) {
    __shared__ float sm[32 * LDP];
    const int tid  = threadIdx.x;
    const int wave = tid >> 6, lane = tid & 63;
    const int quad = lane >> 4, l16 = lane & 15;
    const int rowA = min((int)blockIdx.x * 32 + wave * 16 + l16, M - 1);

    // ---- phase 1 ----
    {
        f32x4 acc1[16];
#pragma unroll
        for (int i = 0; i < 16; i++) acc1[i] = (f32x4){0.f, 0.f, 0.f, 0.f};
#pragma unroll
        for (int h = 0; h < HEADS; h++) {
            const float* Arow = aggx + ((size_t)rowA * HEADS + h) * IN_DIM;
#pragma unroll
            for (int kk = 0; kk < 4; kk++) {
                const int k0 = kk * 32 + quad * 8;
                float a8[8];
                *(float4*)&a8[0] = *(const float4*)&Arow[k0];
                *(float4*)&a8[4] = *(const float4*)&Arow[k0 + 4];
                bf16x8 ah, al;
#pragma unroll
                for (int j = 0; j < 8; j++) {
                    const __bf16 hh = (__bf16)a8[j];
                    ah[j] = hh;
                    al[j] = (__bf16)(a8[j] - (float)hh);
                }
#pragma unroll
                for (int t = 0; t < 4; t++) {
                    const size_t bi = (size_t)h * W1_FRAG +
                                      ((size_t)(t * 4 + kk) * 64 + lane) * 8;
                    bf16x8 bhv = *(const bf16x8*)&B1h[bi];
                    bf16x8 blv = *(const bf16x8*)&B1l[bi];
                    acc1[h*4+t] = __builtin_amdgcn_mfma_f32_16x16x32_bf16(ah, bhv, acc1[h*4+t], 0, 0, 0);
                    acc1[h*4+t] = __builtin_amdgcn_mfma_f32_16x16x32_bf16(al, bhv, acc1[h*4+t], 0, 0, 0);
                    acc1[h*4+t] = __builtin_amdgcn_mfma_f32_16x16x32_bf16(ah, blv, acc1[h*4+t], 0, 0, 0);
                }
            }
        }
        // ELU(+b1) -> LDS (C/D layout: row = wave*16 + quad*4 + r, col)
        const int lrow = wave * 16 + quad * 4;
#pragma unroll
        for (int h = 0; h < HEADS; h++) {
#pragma unroll
            for (int t = 0; t < 4; t++) {
                const int c = h * 64 + t * 16 + l16;
                const float bb = b1[c];
#pragma unroll
                for (int r = 0; r < 4; r++) {
                    sm[(lrow + r) * LDP + c] = eluf(acc1[h*4+t][r] + bb);
                }
            }
        }
    }
    __syncthreads();

    // ---- phase 2: A-fragments straight from LDS (row = wave*16 + l16) ----
    f32x4 acc2[8];
#pragma unroll
    for (int t = 0; t < 8; t++) acc2[t] = (f32x4){0.f, 0.f, 0.f, 0.f};
    const int arow = (wave * 16 + l16) * LDP;
#pragma unroll
    for (int kk = 0; kk < 8; kk++) {
        const int k0 = kk * 32 + quad * 8;
        float a8[8];
        *(float4*)&a8[0] = *(const float4*)&sm[arow + k0];
        *(float4*)&a8[4] = *(const float4*)&sm[arow + k0 + 4];
        bf16x8 ah, al;
#pragma unroll
        for (int j = 0; j < 8; j++) {
            const __bf16 hh = (__bf16)a8[j];
            ah[j] = hh;
            al[j] = (__bf16)(a8[j] - (float)hh);
        }
#pragma unroll
        for (int t = 0; t < 8; t++) {
            const size_t bi = ((size_t)(t * 8 + kk) * 64 + lane) * 8;
            bf16x8 bhv = *(const bf16x8*)&B2h[bi];
            bf16x8 blv = *(const bf16x8*)&B2l[bi];
            acc2[t] = __builtin_amdgcn_mfma_f32_16x16x32_bf16(ah, bhv, acc2[t], 0, 0, 0);
            acc2[t] = __builtin_amdgcn_mfma_f32_16x16x32_bf16(al, bhv, acc2[t], 0, 0, 0);
            acc2[t] = __builtin_amdgcn_mfma_f32_16x16x32_bf16(ah, blv, acc2[t], 0, 0, 0);
        }
    }

    // store g2 + alpha2 logits (1 head)
    const int rowS = blockIdx.x * 32 + wave * 16 + quad * 4;
#pragma unroll
    for (int t = 0; t < 8; t++) {
#pragma unroll
        for (int r = 0; r < 4; r++) {
            const int rr = rowS + r;
            if (rr < M) g2[(size_t)rr * EMB + t * 16 + l16] = acc2[t][r];
        }
    }
#pragma unroll
    for (int r = 0; r < 4; r++) {
        float ps = 0.f, pd = 0.f;
#pragma unroll
        for (int t = 0; t < 8; t++) {
            const int c = t * 16 + l16;
            ps += acc2[t][r] * avs[c];
            pd += acc2[t][r] * avd[c];
        }
#pragma unroll
        for (int o = 1; o < 16; o <<= 1) {
            ps += __shfl_xor(ps, o);
            pd += __shfl_xor(pd, o);
        }
        const int rr = rowS + r;
        if (l16 == 0 && rr < M) {
            as_out[rr] = ps;
            ad_out[rr] = pd;
        }
    }
}

// ---------------------------------------------------------------------------
// Layer-2 aggregation: one wave per dst node, precomputed scalar weights.
// ---------------------------------------------------------------------------
__global__ __launch_bounds__(256) void agg2_kernel(const int* __restrict__ off,
                                                   const int* __restrict__ col,
                                                   const float* __restrict__ w2,
                                                   const float* __restrict__ g2,
                                                   const float* __restrict__ as2,
                                                   const float* __restrict__ ad2,
                                                   float* __restrict__ out2, int N) {
    const int w = __builtin_amdgcn_readfirstlane((blockIdx.x * 256 + threadIdx.x) >> 6);
    const int lane = threadIdx.x & 63;
    if (w >= N) return;

    float2 acc = make_float2(0.f, 0.f);
    float z = 0.f;
    {   // self-loop
        const float wt = expf(lrelu(as2[w] + ad2[w]));
        float2 hv = *(const float2*)&g2[(size_t)w * EMB + lane * 2];
        acc.x += wt * hv.x; acc.y += wt * hv.y;
        z += wt;
    }
    const int jb = off[w], je = off[w + 1];
    int j = jb;
    for (; j + 3 < je; j += 4) {
        const int s0 = col[j], s1 = col[j + 1], s2 = col[j + 2], s3 = col[j + 3];
        const float w0 = w2[j], w1 = w2[j + 1], w2v = w2[j + 2], w3 = w2[j + 3];
        const float2 v0 = *(const float2*)&g2[(size_t)s0 * EMB + lane * 2];
        const float2 v1 = *(const float2*)&g2[(size_t)s1 * EMB + lane * 2];
        const float2 v2 = *(const float2*)&g2[(size_t)s2 * EMB + lane * 2];
        const float2 v3 = *(const float2*)&g2[(size_t)s3 * EMB + lane * 2];
        acc.x += w0 * v0.x + w1 * v1.x + w2v * v2.x + w3 * v3.x;
        acc.y += w0 * v0.y + w1 * v1.y + w2v * v2.y + w3 * v3.y;
        z += (w0 + w1) + (w2v + w3);
    }
    for (; j < je; j++) {
        const int s0 = col[j];
        const float w0 = w2[j];
        const float2 v0 = *(const float2*)&g2[(size_t)s0 * EMB + lane * 2];
        acc.x += w0 * v0.x; acc.y += w0 * v0.y;
        z += w0;
    }
    const float inv = 1.f / z;
    float2 o = make_float2(acc.x * inv, acc.y * inv);
    *(float2*)&out2[(size_t)w * EMB + lane * 2] = o;
}

// ---------------------------------------------------------------------------
// Global mean pool (782-block run-length form) + divide.
// ---------------------------------------------------------------------------
__global__ __launch_bounds__(128) void pool_kernel(const float* __restrict__ out2,
                                                   const float* __restrict__ b2,
                                                   const int* __restrict__ batch,
                                                   float* __restrict__ pool,
                                                   float* __restrict__ cnt, int N) {
    const int c = threadIdx.x;
    const int n0 = blockIdx.x * 64;
    const int nend = min(n0 + 64, N);
    const float bias = b2[c];
    float acc = 0.f, cacc = 0.f;
    int curg = batch[n0];
    for (int n = n0; n < nend; n++) {
        const int g = batch[n];
        if (g != curg) {
            atomicAdd(&pool[curg * EMB + c], acc);
            if (c == 0) atomicAdd(&cnt[curg], cacc);
            acc = 0.f; cacc = 0.f; curg = g;
        }
        float v = out2[(size_t)n * EMB + c] + bias;
        v = v > 0.f ? v : expm1f(v);
        acc += v;
        cacc += 1.f;
    }
    atomicAdd(&pool[curg * EMB + c], acc);
    if (c == 0) atomicAdd(&cnt[curg], cacc);
}

__global__ __launch_bounds__(256) void div_kernel(const float* __restrict__ pool,
                                                  const float* __restrict__ cnt,
                                                  float* __restrict__ out) {
    const int i = blockIdx.x * 256 + threadIdx.x;
    out[i] = pool[i] / fmaxf(cnt[i >> 7], 1.f);
}

// ---------------------------------------------------------------------------
extern "C" void kernel_launch(void* const* d_in, const int* in_sizes, int n_in,
                              void* d_out, int out_size, void* d_ws, size_t ws_size,
                              hipStream_t stream) {
    const float* x      = (const float*)d_in[0];
    const int*   ei     = (const int*)d_in[1];
    const int*   batch  = (const int*)d_in[3];
    const float* W1     = (const float*)d_in[4];
    const float* a_src1 = (const float*)d_in[5];
    const float* a_dst1 = (const float*)d_in[6];
    const float* b1     = (const float*)d_in[7];
    const float* W2     = (const float*)d_in[8];
    const float* a_src2 = (const float*)d_in[9];
    const float* a_dst2 = (const float*)d_in[10];
    const float* b2     = (const float*)d_in[11];
    float* out = (float*)d_out;

    const int N = N_NODES, E = N_EDGES;

    size_t cur_off = 0;
    auto carve = [&](size_t bytes) {
        size_t o = cur_off;
        cur_off = (cur_off + bytes + 255) & ~(size_t)255;
        return (char*)d_ws + o;
    };
    // zero-init region: deg + pool + cnt
    int* deg     = (int*)carve((size_t)N * 4);
    float* pool  = (float*)carve((size_t)N_GRAPHS * EMB * 4);
    float* cnt   = (float*)carve((size_t)N_GRAPHS * 4);
    const size_t zero_bytes = cur_off;
    int* curp    = (int*)carve((size_t)N * 4);
    int* partial = (int*)carve((size_t)SCAN_BLOCKS * 4);
    __bf16* B1h  = (__bf16*)carve((size_t)HEADS * W1_FRAG * 2);
    __bf16* B1l  = (__bf16*)carve((size_t)HEADS * W1_FRAG * 2);
    __bf16* B2h  = (__bf16*)carve((size_t)F1 * EMB * 2);
    __bf16* B2l  = (__bf16*)carve((size_t)F1 * EMB * 2);
    int* off     = (int*)carve((size_t)(N + 1) * 4);
    int* col     = (int*)carve((size_t)E * 4);
    int* rowd    = (int*)carve((size_t)E * 4);
    float4* w4   = (float4*)carve((size_t)E * 16);
    float* w2    = (float*)carve((size_t)E * 4);
    float* aggx  = (float*)carve((size_t)N * HEADS * IN_DIM * 4);
    float* g2    = (float*)carve((size_t)N * EMB * 4);
    float* out2  = (float*)carve((size_t)N * EMB * 4);
    float* as1   = (float*)carve((size_t)N * HEADS * 4);
    float* ad1   = (float*)carve((size_t)N * HEADS * 4);
    float* as2   = (float*)carve((size_t)N * 4);
    float* ad2   = (float*)carve((size_t)N * 4);

    hipMemsetAsync(d_ws, 0, zero_bytes, stream);

    prep_kernel<<<DEG_BLOCKS + 32, 256, 0, stream>>>(ei, deg, W1, B1h, B1l, W2, B2h, B2l);

    scanA_kernel<<<SCAN_BLOCKS, 256, 0, stream>>>(deg, off, partial, N);
    scanB_kernel<<<1, 256, 0, stream>>>(partial, &off[N]);
    scanC_kernel<<<SCAN_BLOCKS, 256, 0, stream>>>(off, partial, curp, N);

    // gemm1 (x -> as1/ad1), then scatter fused with edge-weight computation
    gemm1_kernel<<<(N + 63) / 64, 256, 0, stream>>>(x, B1h, B1l, a_src1, a_dst1,
                                                    as1, ad1, N);
    scatter_w1_kernel<<<DEG_BLOCKS, 256, 0, stream>>>(ei, off, curp, col, rowd,
                                                      as1, ad1, w4, E);

    agg1x_kernel<<<(N + 3) / 4, 256, 0, stream>>>(off, col, w4, x, as1, ad1, aggx, N);

    // fused: (aggx @ W1 -> ELU -> @ W2) + alpha2, no out1 round-trip
    gemm12_kernel<<<(N + 31) / 32, 128, 0, stream>>>(aggx, B1h, B1l, b1, B2h, B2l,
                                                     a_src2, a_dst2, g2, as2, ad2, N);

    w2_kernel<<<DEG_BLOCKS, 256, 0, stream>>>(col, rowd, as2, ad2, w2, E);
    agg2_kernel<<<(N + 3) / 4, 256, 0, stream>>>(off, col, w2, g2, as2, ad2, out2, N);

    pool_kernel<<<(N + 63) / 64, 128, 0, stream>>>(out2, b2, batch, pool, cnt, N);
    div_kernel<<<(N_GRAPHS * EMB) / 256, 256, 0, stream>>>(pool, cnt, out);
}